// Round 16
// baseline (1472.838 us; speedup 1.0000x reference)
//
#include <hip/hip_runtime.h>
#include <hip/hip_bf16.h>

// Problem constants
#define BSZ 4
#define SEQ 2048
#define NH  16
#define DH  64
#define TOK (BSZ*SEQ)          // 8192 tokens
#define PROJC (NH*DH)          // 1024

typedef __bf16 bf16x8 __attribute__((ext_vector_type(8)));
typedef float  f32x4  __attribute__((ext_vector_type(4)));
typedef float  f32x16 __attribute__((ext_vector_type(16)));
typedef unsigned int uint4v __attribute__((ext_vector_type(4)));
typedef unsigned int uint2v __attribute__((ext_vector_type(2)));

__device__ inline unsigned short f2bf(float f) {
    __bf16 h = (__bf16)f;
    return __builtin_bit_cast(unsigned short, h);
}

__device__ inline bf16x8 ld8(const unsigned short* p) {
    return __builtin_bit_cast(bf16x8, *reinterpret_cast<const uint4v*>(p));
}

// raw v_exp_f32 (2^x): 1 instruction, no OCML range/denorm guards.
__device__ inline float fexp2(float x) {
    float r;
    asm("v_exp_f32 %0, %1" : "=v"(r) : "v"(x));
    return r;
}

// async global -> LDS, 16B per lane; LDS dest = wave-uniform base + lane*16
__device__ inline void gload16(const unsigned short* g, unsigned short* l) {
    __builtin_amdgcn_global_load_lds(
        (__attribute__((address_space(1))) void*)g,
        (__attribute__((address_space(3))) void*)l, 16, 0, 0);
}

// ---------------- fused prep: conv (f32->bf16) + 4x weight transpose -------
__global__ __launch_bounds__(256) void prep_kernel(const float* __restrict__ q,
                                                   const float* __restrict__ k,
                                                   const float* __restrict__ Wq,
                                                   const float* __restrict__ Wk,
                                                   const float* __restrict__ Wv,
                                                   const float* __restrict__ Wfc,
                                                   unsigned short* __restrict__ qbf,
                                                   unsigned short* __restrict__ kbf,
                                                   unsigned short* __restrict__ WqT,
                                                   unsigned short* __restrict__ WkT,
                                                   unsigned short* __restrict__ WvT,
                                                   unsigned short* __restrict__ WfcT) {
    int bx = blockIdx.x;
    if (bx < 4096) {
        int idx = (bx & 2047) * 256 + threadIdx.x;
        if (bx < 2048) qbf[idx] = f2bf(q[idx]);
        else           kbf[idx] = f2bf(k[idx]);
        return;
    }
    bx -= 4096;
    const float* W; unsigned short* WT; int cols; int base;
    if      (bx < 256) { W = Wq;  WT = WqT;  cols = PROJC; base = bx; }
    else if (bx < 512) { W = Wk;  WT = WkT;  cols = PROJC; base = bx - 256; }
    else if (bx < 768) { W = Wv;  WT = WvT;  cols = PROJC; base = bx - 512; }
    else               { W = Wfc; WT = WfcT; cols = 64;    base = bx - 768; }
    int idx = base * 256 + threadIdx.x;
    int c = idx % cols, kk = idx / cols;
    WT[c * 64 + kk] = f2bf(W[kk * cols + c]);
}

// ---------------- mask bit-pack: int32 [b][q][k] -> uint64 bitrows ---------
__global__ __launch_bounds__(256) void maskpack_kernel(const int* __restrict__ mask,
                                                       unsigned long long* __restrict__ mbits) {
    size_t gid = (size_t)blockIdx.x * 256 + threadIdx.x;
    int lane = threadIdx.x & 63;
    unsigned long long bal = __ballot(mask[gid] != 0);
    if (lane == 0) mbits[gid >> 6] = bal;
}

// ---------------- fused projections: Q, K, Vt in one pass ------------------
__global__ __launch_bounds__(256) void proj_kernel(const unsigned short* __restrict__ qbf,
                                                   const unsigned short* __restrict__ kbf,
                                                   const unsigned short* __restrict__ WqT,
                                                   const unsigned short* __restrict__ WkT,
                                                   const unsigned short* __restrict__ WvT,
                                                   unsigned short* __restrict__ Qo,
                                                   unsigned short* __restrict__ Ko,
                                                   unsigned short* __restrict__ Vto) {
    __shared__ __align__(16) unsigned short TQ[64][72];
    __shared__ __align__(16) unsigned short TK[64][72];
    __shared__ __align__(16) unsigned short TV[64][72];
    int tid = threadIdx.x, w = tid >> 6, lane = tid & 63;
    int l15 = lane & 15, l4 = lane >> 4;
    int r0 = blockIdx.x * 64 + w * 16;
    int h = blockIdx.y;
    int c0 = h * 64;
    int b = blockIdx.x >> 5;
    size_t bh = (size_t)(b * NH + h);

    const unsigned short* aq = qbf + (r0 + l15) * 64 + l4 * 8;
    bf16x8 a0q = ld8(aq), a1q = ld8(aq + 32);
    const unsigned short* ak = kbf + (r0 + l15) * 64 + l4 * 8;
    bf16x8 a0k = ld8(ak), a1k = ld8(ak + 32);

    #pragma unroll
    for (int ct = 0; ct < 4; ++ct) {
        int wrow = (c0 + ct * 16 + l15) * 64 + l4 * 8;
        bf16x8 q0 = ld8(WqT + wrow), q1 = ld8(WqT + wrow + 32);
        bf16x8 k0 = ld8(WkT + wrow), k1 = ld8(WkT + wrow + 32);
        bf16x8 v0 = ld8(WvT + wrow), v1 = ld8(WvT + wrow + 32);
        f32x4 accq = {0.f,0.f,0.f,0.f}, acck = accq, accv = accq;
        accq = __builtin_amdgcn_mfma_f32_16x16x32_bf16(q0, a0q, accq, 0, 0, 0);
        accq = __builtin_amdgcn_mfma_f32_16x16x32_bf16(q1, a1q, accq, 0, 0, 0);
        acck = __builtin_amdgcn_mfma_f32_16x16x32_bf16(k0, a0k, acck, 0, 0, 0);
        acck = __builtin_amdgcn_mfma_f32_16x16x32_bf16(k1, a1k, acck, 0, 0, 0);
        accv = __builtin_amdgcn_mfma_f32_16x16x32_bf16(a0k, v0, accv, 0, 0, 0);
        accv = __builtin_amdgcn_mfma_f32_16x16x32_bf16(a1k, v1, accv, 0, 0, 0);
        uint2v pq, pk, pv;
        pq.x = (unsigned)f2bf(accq[0]) | ((unsigned)f2bf(accq[1]) << 16);
        pq.y = (unsigned)f2bf(accq[2]) | ((unsigned)f2bf(accq[3]) << 16);
        pk.x = (unsigned)f2bf(acck[0]) | ((unsigned)f2bf(acck[1]) << 16);
        pk.y = (unsigned)f2bf(acck[2]) | ((unsigned)f2bf(acck[3]) << 16);
        pv.x = (unsigned)f2bf(accv[0]) | ((unsigned)f2bf(accv[1]) << 16);
        pv.y = (unsigned)f2bf(accv[2]) | ((unsigned)f2bf(accv[3]) << 16);
        *reinterpret_cast<uint2v*>(&TQ[w * 16 + l15][ct * 16 + l4 * 4]) = pq;
        *reinterpret_cast<uint2v*>(&TK[w * 16 + l15][ct * 16 + l4 * 4]) = pk;
        *reinterpret_cast<uint2v*>(&TV[ct * 16 + l15][w * 16 + l4 * 4]) = pv;
    }
    __syncthreads();

    int rl8 = tid >> 3, chunk = tid & 7;
    int q0 = (blockIdx.x & 31) * 64;
    #pragma unroll
    for (int p = 0; p < 2; ++p) {
        int rl = p * 32 + rl8;
        uint4v vq = *reinterpret_cast<const uint4v*>(&TQ[rl][chunk * 8]);
        uint4v vk = *reinterpret_cast<const uint4v*>(&TK[rl][chunk * 8]);
        uint4v vv = *reinterpret_cast<const uint4v*>(&TV[rl][chunk * 8]);
        *reinterpret_cast<uint4v*>(Qo  + (bh * SEQ + q0 + rl) * 64 + chunk * 8) = vq;
        *reinterpret_cast<uint4v*>(Ko  + (bh * SEQ + q0 + rl) * 64 + chunk * 8) = vk;
        *reinterpret_cast<uint4v*>(Vto + (bh * 64 + rl) * SEQ + q0 + chunk * 8) = vv;
    }
}

// ---------------- flash attention, in-block split-K + fused FC -------------
// Grid 1024 (XCD-swizzled), 512 threads = 8 waves. Block covers 128 q rows of
// one bh; waves 0-3 process keys 0..1023, waves 4-7 keys 1024..2047 (wave w
// and w+4 own the same 32 q rows). Static max m=0 makes partials EXACT sums:
// O = (O_A + O_B) / (ell_A + ell_B). KBLK=32, per-group double-buffered K/V
// in LDS via global_load_lds (linear dest, XOR-swizzled source, swizzled
// reads). Swapped QK^T; PV A-frag = lane's own packed words (k-subset trick);
// ell via ones-MFMA. R9-proven softmax (mask as 0/-inf fma bias + v_exp_f32).
// Epilogue: group A dumps o/ell lane-linear f32 to LDS; group B adds, then
// runs the R15-verified FC/tanh epilogue. Fully-masked rows -> ell==0 -> 0.
__global__ __launch_bounds__(512, 8) void attn_kernel(const unsigned short* __restrict__ Q,
                                                      const unsigned short* __restrict__ K,
                                                      const unsigned short* __restrict__ Vt,
                                                      const unsigned long long* __restrict__ mbits,
                                                      const unsigned short* __restrict__ WfcT,
                                                      const float* __restrict__ bfc,
                                                      float* __restrict__ out) {
    // main loop: [group g][ K buf0 | K buf1 | V buf0 | V buf1 ] 4KB each = 32KB
    // epilogue: 4 regions x 8448B (o 8192 + ell 128, padded) = 33792B
    __shared__ __align__(16) unsigned char smem[33792];
    int tid = threadIdx.x, w = tid >> 6, lane = tid & 63;
    int l31 = lane & 31, hi = lane >> 5;
    int hi4 = hi * 4;
    int g = w >> 2, gw = w & 3;
    int kbase = g * 1024;

    // XCD-aware swizzle: 1024 % 8 == 0, bijective
    int bid = blockIdx.x;
    int swz = (bid & 7) * 128 + (bid >> 3);
    int bh = swz >> 4;              // 0..63
    int qt = swz & 15;              // 0..15
    int b = bh >> 4;
    int qbase = qt * 128 + gw * 32;

    const unsigned short* Qh = Q  + (size_t)bh * SEQ * 64;
    const unsigned short* Kh = K  + (size_t)bh * SEQ * 64;
    const unsigned short* Vh = Vt + (size_t)bh * 64 * SEQ;
    // u32 mask words: 64 per q row; group g uses words g*32 .. g*32+31
    const unsigned* mrow32 = (const unsigned*)mbits +
        ((size_t)b * SEQ + qbase + l31) * 64 + g * 32;

    unsigned short* Kb0 = (unsigned short*)(smem + g * 16384);
    unsigned short* Kb1 = Kb0 + 2048;
    unsigned short* Vb0 = Kb0 + 4096;
    unsigned short* Vb1 = Kb0 + 6144;

    // staging geometry (per group: 256 threads cover K 4KB + V 4KB per tile)
    int krowS = (gw << 3) + (lane >> 3);        // 0..31
    int scK   = (lane & 7) ^ (krowS & 7);
    int vrowS = (gw << 4) + (lane >> 2);        // 0..63
    int scV   = (lane & 3) ^ (vrowS & 3);

    // Q B-frags: lane holds Q[qbase+l31][s*16 + hi*8 + j]
    bf16x8 qf[4];
    #pragma unroll
    for (int s = 0; s < 4; ++s)
        qf[s] = ld8(Qh + (size_t)(qbase + l31) * 64 + s * 16 + hi * 8);

    bf16x8 ones;
    #pragma unroll
    for (int i = 0; i < 8; ++i) ones[i] = (__bf16)1.0f;

    f32x16 o0 = {0.f,0.f,0.f,0.f,0.f,0.f,0.f,0.f,0.f,0.f,0.f,0.f,0.f,0.f,0.f,0.f};
    f32x16 o1 = o0;
    f32x16 ellD = o0;
    const float C = 0.125f * 1.44269504088896f;   // scale * log2(e)

    auto stage_tile = [&](unsigned short* Kd, unsigned short* Vd, int t) {
        int kk = kbase + t * 32;
        gload16(Kh + (size_t)(kk + krowS) * 64 + scK * 8, Kd + gw * 512);
        gload16(Vh + (size_t)vrowS * SEQ + kk + scV * 8, Vd + gw * 512);
    };

    auto compute_tile = [&](const unsigned short* Kc, const unsigned short* Vc, int t) {
        unsigned mword = mrow32[t];
        f32x16 z = {0.f,0.f,0.f,0.f,0.f,0.f,0.f,0.f,0.f,0.f,0.f,0.f,0.f,0.f,0.f,0.f};
        int krow = l31;
        #pragma unroll
        for (int s = 0; s < 4; ++s) {
            const unsigned short* kp =
                Kc + krow * 64 + ((((s << 1) + hi) ^ (krow & 7)) << 3);
            z = __builtin_amdgcn_mfma_f32_32x32x16_bf16(ld8(kp), qf[s], z, 0, 0, 0);
        }
        unsigned wsh = mword >> hi4;                 // lane's bits at 0..27
        unsigned wpk[8];
        #pragma unroll
        for (int rq = 0; rq < 4; ++rq) {
            #pragma unroll
            for (int rr = 0; rr < 2; ++rr) {
                float e[2];
                #pragma unroll
                for (int j = 0; j < 2; ++j) {
                    int pos = rq * 8 + 2 * rr + j;           // compile-time
                    int sx = (int)(wsh << (31 - pos)) >> 31; // v_bfe_i32
                    float bias = __builtin_bit_cast(float, (unsigned)sx & 0xFF800000u);
                    e[j] = fexp2(__builtin_fmaf(z[rq * 4 + 2 * rr + j], C, bias));
                }
                wpk[rq * 2 + rr] = (unsigned)f2bf(e[0]) | ((unsigned)f2bf(e[1]) << 16);
            }
        }
        __builtin_amdgcn_s_setprio(1);
        #pragma unroll
        for (int sl = 0; sl < 2; ++sl) {
            uint4v aw = {wpk[sl * 4 + 0], wpk[sl * 4 + 1],
                         wpk[sl * 4 + 2], wpk[sl * 4 + 3]};
            bf16x8 af = __builtin_bit_cast(bf16x8, aw);
            ellD = __builtin_amdgcn_mfma_f32_32x32x16_bf16(af, ones, ellD, 0, 0, 0);
            // V rows 32 cols wide (64B = 4 chunks), slot = chunk ^ (row & 3)
            int c0i = (((2 * sl)     ^ (l31 & 3)) << 3);
            int c1i = (((2 * sl + 1) ^ (l31 & 3)) << 3);
            {   // dtile 0: vrow = l31   ((32+l31)&3 == l31&3, so c?i shared)
                uint2v lo = *reinterpret_cast<const uint2v*>(Vc + l31 * 32 + c0i + hi4);
                uint2v hh = *reinterpret_cast<const uint2v*>(Vc + l31 * 32 + c1i + hi4);
                uint4v vw = {lo.x, lo.y, hh.x, hh.y};
                o0 = __builtin_amdgcn_mfma_f32_32x32x16_bf16(
                    af, __builtin_bit_cast(bf16x8, vw), o0, 0, 0, 0);
            }
            {   // dtile 1: vrow = 32 + l31
                uint2v lo = *reinterpret_cast<const uint2v*>(Vc + (32 + l31) * 32 + c0i + hi4);
                uint2v hh = *reinterpret_cast<const uint2v*>(Vc + (32 + l31) * 32 + c1i + hi4);
                uint4v vw = {lo.x, lo.y, hh.x, hh.y};
                o1 = __builtin_amdgcn_mfma_f32_32x32x16_bf16(
                    af, __builtin_bit_cast(bf16x8, vw), o1, 0, 0, 0);
            }
        }
        __builtin_amdgcn_s_setprio(0);
    };

    // prologue: stage tile 0 into buffer 0
    stage_tile(Kb0, Vb0, 0);
    __syncthreads();

    // 32 tiles per group, unrolled x2 (compile-time buffer roles)
    for (int t = 0; t < 32; t += 2) {
        stage_tile(Kb1, Vb1, t + 1);
        compute_tile(Kb0, Vb0, t);
        __syncthreads();
        if (t + 2 < 32) stage_tile(Kb0, Vb0, t + 2);
        compute_tile(Kb1, Vb1, t + 1);
        __syncthreads();
    }

    // ==== split-K combine ====
    // group A dumps partials lane-linear (conflict-free, no transpose)
    if (w < 4) {
        float* R = (float*)(smem + (size_t)w * 8448);
        #pragma unroll
        for (int reg = 0; reg < 16; ++reg) {
            R[reg * 64 + lane]        = o0[reg];
            R[(16 + reg) * 64 + lane] = o1[reg];
        }
        if (l31 == 0) {
            #pragma unroll
            for (int reg = 0; reg < 16; ++reg)
                R[2048 + (reg & 3) + 8 * (reg >> 2) + hi4] = ellD[reg];
        }
    }
    __syncthreads();
    if (w >= 4) {
        const float* R = (const float*)(smem + (size_t)(w - 4) * 8448);
        #pragma unroll
        for (int reg = 0; reg < 16; ++reg) {
            o0[reg]   += R[reg * 64 + lane];
            o1[reg]   += R[(16 + reg) * 64 + lane];
            ellD[reg] += R[2048 + (reg & 3) + 8 * (reg >> 2) + hi4];
        }
    }
    __syncthreads();   // fences partial reads before bf16 reuse of the region
    if (w >= 4) {
        // ==== fused epilogue: out = tanh(O @ Wfc + bfc) (R15-verified) ====
        unsigned short* Ot = (unsigned short*)(smem + (size_t)(w - 4) * 8448);
        #pragma unroll
        for (int reg = 0; reg < 16; ++reg) {
            float l = ellD[reg];
            float rcp = (l == 0.f) ? 0.f : __builtin_amdgcn_rcpf(l);
            int ql = (reg & 3) + 8 * (reg >> 2) + hi4;   // 0..31
            int ch0 = (l31 >> 3) ^ (ql & 7);
            int ch1 = ((l31 >> 3) + 4) ^ (ql & 7);
            Ot[ql * 64 + ch0 * 8 + (l31 & 7)] = f2bf(o0[reg] * rcp);
            Ot[ql * 64 + ch1 * 8 + (l31 & 7)] = f2bf(o1[reg] * rcp);
        }
        bf16x8 of[4];
        #pragma unroll
        for (int s = 0; s < 4; ++s) {
            int cs = (s * 2 + hi) ^ (l31 & 7);
            of[s] = ld8(Ot + l31 * 64 + cs * 8);
        }
        size_t orow = ((size_t)b * SEQ + qbase + l31) * NH + (bh & 15);
        #pragma unroll
        for (int ctile = 0; ctile < 2; ++ctile) {
            f32x16 acc = {0.f,0.f,0.f,0.f,0.f,0.f,0.f,0.f,0.f,0.f,0.f,0.f,0.f,0.f,0.f,0.f};
            #pragma unroll
            for (int s = 0; s < 4; ++s) {
                bf16x8 wf = ld8(WfcT + (ctile * 32 + l31) * 64 + s * 16 + hi * 8);
                acc = __builtin_amdgcn_mfma_f32_32x32x16_bf16(wf, of[s], acc, 0, 0, 0);
            }
            #pragma unroll
            for (int gq = 0; gq < 4; ++gq) {   // regs 4gq.. -> c = ctile*32+8gq+4hi+0..3
                int cbase = ctile * 32 + 8 * gq + hi4;
                f32x4 bv = *reinterpret_cast<const f32x4*>(bfc + cbase);
                f32x4 st;
                #pragma unroll
                for (int r = 0; r < 4; ++r) {
                    float x = acc[gq * 4 + r] + bv[r];
                    x = fminf(fmaxf(x, -9.f), 9.f);
                    float t = fexp2(x * 2.88539008177793f);     // 2*log2(e)
                    st[r] = (t - 1.f) * __builtin_amdgcn_rcpf(t + 1.f);
                }
                *reinterpret_cast<f32x4*>(out + orow * 64 + cbase) = st;
            }
        }
    }
}

extern "C" void kernel_launch(void* const* d_in, const int* in_sizes, int n_in,
                              void* d_out, int out_size, void* d_ws, size_t ws_size,
                              hipStream_t stream) {
    const float* q_origin = (const float*)d_in[0];
    const float* k_origin = (const float*)d_in[1];
    const int*   mask     = (const int*)d_in[2];
    const float* Wq       = (const float*)d_in[3];
    const float* Wk       = (const float*)d_in[4];
    const float* Wv       = (const float*)d_in[5];
    const float* Wfc      = (const float*)d_in[6];
    const float* bfc      = (const float*)d_in[7];
    float* out = (float*)d_out;

    unsigned short* ws = (unsigned short*)d_ws;
    unsigned short* qbf  = ws;                 // dead after proj
    unsigned short* kbf  = qbf  + TOK * DH;    // dead after proj
    unsigned short* WqT  = kbf  + TOK * DH;
    unsigned short* WkT  = WqT  + 64 * PROJC;
    unsigned short* WvT  = WkT  + 64 * PROJC;
    unsigned short* WfcT = WvT  + 64 * PROJC;
    unsigned short* Qb   = WfcT + 64 * 64;
    unsigned short* Kb   = Qb   + (size_t)BSZ * NH * SEQ * DH;
    unsigned short* Vtb  = Kb   + (size_t)BSZ * NH * SEQ * DH;
    unsigned long long* mbits = (unsigned long long*)d_ws;  // aliases qbf/kbf

    prep_kernel<<<4880, 256, 0, stream>>>(q_origin, k_origin, Wq, Wk, Wv, Wfc,
                                          qbf, kbf, WqT, WkT, WvT, WfcT);
    proj_kernel<<<dim3(TOK / 64, NH), 256, 0, stream>>>(
        qbf, kbf, WqT, WkT, WvT, Qb, Kb, Vtb);
    maskpack_kernel<<<(size_t)BSZ * SEQ * SEQ / 256, 256, 0, stream>>>(mask, mbits);
    attn_kernel<<<1024, 512, 0, stream>>>(Qb, Kb, Vtb, mbits, WfcT, bfc, out);
}

// Round 17
// 180.954 us; speedup vs baseline: 8.1393x; 8.1393x over previous
//
#include <hip/hip_runtime.h>
#include <hip/hip_bf16.h>

// Problem constants
#define BSZ 4
#define SEQ 2048
#define NH  16
#define DH  64
#define TOK (BSZ*SEQ)          // 8192 tokens
#define PROJC (NH*DH)          // 1024

typedef __bf16 bf16x8 __attribute__((ext_vector_type(8)));
typedef float  f32x4  __attribute__((ext_vector_type(4)));
typedef float  f32x16 __attribute__((ext_vector_type(16)));
typedef unsigned int uint4v __attribute__((ext_vector_type(4)));
typedef unsigned int uint2v __attribute__((ext_vector_type(2)));

__device__ inline unsigned short f2bf(float f) {
    __bf16 h = (__bf16)f;
    return __builtin_bit_cast(unsigned short, h);
}

__device__ inline bf16x8 ld8(const unsigned short* p) {
    return __builtin_bit_cast(bf16x8, *reinterpret_cast<const uint4v*>(p));
}

// raw v_exp_f32 (2^x): 1 instruction, no OCML range/denorm guards.
__device__ inline float fexp2(float x) {
    float r;
    asm("v_exp_f32 %0, %1" : "=v"(r) : "v"(x));
    return r;
}

// async global -> LDS, 16B per lane; LDS dest = wave-uniform base + lane*16
__device__ inline void gload16(const unsigned short* g, unsigned short* l) {
    __builtin_amdgcn_global_load_lds(
        (__attribute__((address_space(1))) void*)g,
        (__attribute__((address_space(3))) void*)l, 16, 0, 0);
}

// ---------------- fused prep: conv (f32->bf16) + 4x weight transpose -------
__global__ __launch_bounds__(256) void prep_kernel(const float* __restrict__ q,
                                                   const float* __restrict__ k,
                                                   const float* __restrict__ Wq,
                                                   const float* __restrict__ Wk,
                                                   const float* __restrict__ Wv,
                                                   const float* __restrict__ Wfc,
                                                   unsigned short* __restrict__ qbf,
                                                   unsigned short* __restrict__ kbf,
                                                   unsigned short* __restrict__ WqT,
                                                   unsigned short* __restrict__ WkT,
                                                   unsigned short* __restrict__ WvT,
                                                   unsigned short* __restrict__ WfcT) {
    int bx = blockIdx.x;
    if (bx < 4096) {
        int idx = (bx & 2047) * 256 + threadIdx.x;
        if (bx < 2048) qbf[idx] = f2bf(q[idx]);
        else           kbf[idx] = f2bf(k[idx]);
        return;
    }
    bx -= 4096;
    const float* W; unsigned short* WT; int cols; int base;
    if      (bx < 256) { W = Wq;  WT = WqT;  cols = PROJC; base = bx; }
    else if (bx < 512) { W = Wk;  WT = WkT;  cols = PROJC; base = bx - 256; }
    else if (bx < 768) { W = Wv;  WT = WvT;  cols = PROJC; base = bx - 512; }
    else               { W = Wfc; WT = WfcT; cols = 64;    base = bx - 768; }
    int idx = base * 256 + threadIdx.x;
    int c = idx % cols, kk = idx / cols;
    WT[c * 64 + kk] = f2bf(W[kk * cols + c]);
}

// ---------------- mask bit-pack: int32 [b][q][k] -> uint64 bitrows ---------
__global__ __launch_bounds__(256) void maskpack_kernel(const int* __restrict__ mask,
                                                       unsigned long long* __restrict__ mbits) {
    size_t gid = (size_t)blockIdx.x * 256 + threadIdx.x;
    int lane = threadIdx.x & 63;
    unsigned long long bal = __ballot(mask[gid] != 0);
    if (lane == 0) mbits[gid >> 6] = bal;
}

// ---------------- fused projections: Q, K, Vt in one pass ------------------
__global__ __launch_bounds__(256) void proj_kernel(const unsigned short* __restrict__ qbf,
                                                   const unsigned short* __restrict__ kbf,
                                                   const unsigned short* __restrict__ WqT,
                                                   const unsigned short* __restrict__ WkT,
                                                   const unsigned short* __restrict__ WvT,
                                                   unsigned short* __restrict__ Qo,
                                                   unsigned short* __restrict__ Ko,
                                                   unsigned short* __restrict__ Vto) {
    __shared__ __align__(16) unsigned short TQ[64][72];
    __shared__ __align__(16) unsigned short TK[64][72];
    __shared__ __align__(16) unsigned short TV[64][72];
    int tid = threadIdx.x, w = tid >> 6, lane = tid & 63;
    int l15 = lane & 15, l4 = lane >> 4;
    int r0 = blockIdx.x * 64 + w * 16;
    int h = blockIdx.y;
    int c0 = h * 64;
    int b = blockIdx.x >> 5;
    size_t bh = (size_t)(b * NH + h);

    const unsigned short* aq = qbf + (r0 + l15) * 64 + l4 * 8;
    bf16x8 a0q = ld8(aq), a1q = ld8(aq + 32);
    const unsigned short* ak = kbf + (r0 + l15) * 64 + l4 * 8;
    bf16x8 a0k = ld8(ak), a1k = ld8(ak + 32);

    #pragma unroll
    for (int ct = 0; ct < 4; ++ct) {
        int wrow = (c0 + ct * 16 + l15) * 64 + l4 * 8;
        bf16x8 q0 = ld8(WqT + wrow), q1 = ld8(WqT + wrow + 32);
        bf16x8 k0 = ld8(WkT + wrow), k1 = ld8(WkT + wrow + 32);
        bf16x8 v0 = ld8(WvT + wrow), v1 = ld8(WvT + wrow + 32);
        f32x4 accq = {0.f,0.f,0.f,0.f}, acck = accq, accv = accq;
        accq = __builtin_amdgcn_mfma_f32_16x16x32_bf16(q0, a0q, accq, 0, 0, 0);
        accq = __builtin_amdgcn_mfma_f32_16x16x32_bf16(q1, a1q, accq, 0, 0, 0);
        acck = __builtin_amdgcn_mfma_f32_16x16x32_bf16(k0, a0k, acck, 0, 0, 0);
        acck = __builtin_amdgcn_mfma_f32_16x16x32_bf16(k1, a1k, acck, 0, 0, 0);
        accv = __builtin_amdgcn_mfma_f32_16x16x32_bf16(a0k, v0, accv, 0, 0, 0);
        accv = __builtin_amdgcn_mfma_f32_16x16x32_bf16(a1k, v1, accv, 0, 0, 0);
        uint2v pq, pk, pv;
        pq.x = (unsigned)f2bf(accq[0]) | ((unsigned)f2bf(accq[1]) << 16);
        pq.y = (unsigned)f2bf(accq[2]) | ((unsigned)f2bf(accq[3]) << 16);
        pk.x = (unsigned)f2bf(acck[0]) | ((unsigned)f2bf(acck[1]) << 16);
        pk.y = (unsigned)f2bf(acck[2]) | ((unsigned)f2bf(acck[3]) << 16);
        pv.x = (unsigned)f2bf(accv[0]) | ((unsigned)f2bf(accv[1]) << 16);
        pv.y = (unsigned)f2bf(accv[2]) | ((unsigned)f2bf(accv[3]) << 16);
        *reinterpret_cast<uint2v*>(&TQ[w * 16 + l15][ct * 16 + l4 * 4]) = pq;
        *reinterpret_cast<uint2v*>(&TK[w * 16 + l15][ct * 16 + l4 * 4]) = pk;
        *reinterpret_cast<uint2v*>(&TV[ct * 16 + l15][w * 16 + l4 * 4]) = pv;
    }
    __syncthreads();

    int rl8 = tid >> 3, chunk = tid & 7;
    int q0 = (blockIdx.x & 31) * 64;
    #pragma unroll
    for (int p = 0; p < 2; ++p) {
        int rl = p * 32 + rl8;
        uint4v vq = *reinterpret_cast<const uint4v*>(&TQ[rl][chunk * 8]);
        uint4v vk = *reinterpret_cast<const uint4v*>(&TK[rl][chunk * 8]);
        uint4v vv = *reinterpret_cast<const uint4v*>(&TV[rl][chunk * 8]);
        *reinterpret_cast<uint4v*>(Qo  + (bh * SEQ + q0 + rl) * 64 + chunk * 8) = vq;
        *reinterpret_cast<uint4v*>(Ko  + (bh * SEQ + q0 + rl) * 64 + chunk * 8) = vk;
        *reinterpret_cast<uint4v*>(Vto + (bh * 64 + rl) * SEQ + q0 + chunk * 8) = vv;
    }
}

// ---------------- flash attention, in-block split-K + fused FC -------------
// Grid 1024 (XCD-swizzled), 512 threads = 8 waves. Block covers 128 q rows of
// one bh; waves 0-3 process keys 0..1023, waves 4-7 keys 1024..2047 (wave w
// and w+4 own the same 32 q rows). Static max m=0 makes partials EXACT sums:
// O = (O_A + O_B) / (ell_A + ell_B). KBLK=32, per-group double-buffered K/V
// in LDS via global_load_lds. launch_bounds (512,4): VGPR cap 128 (allocator
// lands ~64, NO spill — R16's (512,8) forced 32 VGPR and 6.9 GB of scratch
// traffic); 8 waves/SIMD still achievable at 64 VGPR, LDS allows 4 blk/CU.
__global__ __launch_bounds__(512, 4) void attn_kernel(const unsigned short* __restrict__ Q,
                                                      const unsigned short* __restrict__ K,
                                                      const unsigned short* __restrict__ Vt,
                                                      const unsigned long long* __restrict__ mbits,
                                                      const unsigned short* __restrict__ WfcT,
                                                      const float* __restrict__ bfc,
                                                      float* __restrict__ out) {
    // main loop: [group g][ K buf0 | K buf1 | V buf0 | V buf1 ] 4KB each = 32KB
    // epilogue: 4 regions x 8448B (o 8192 + ell 128, padded) = 33792B
    __shared__ __align__(16) unsigned char smem[33792];
    int tid = threadIdx.x, w = tid >> 6, lane = tid & 63;
    int l31 = lane & 31, hi = lane >> 5;
    int hi4 = hi * 4;
    int g = w >> 2, gw = w & 3;
    int kbase = g * 1024;

    // XCD-aware swizzle: 1024 % 8 == 0, bijective
    int bid = blockIdx.x;
    int swz = (bid & 7) * 128 + (bid >> 3);
    int bh = swz >> 4;              // 0..63
    int qt = swz & 15;              // 0..15
    int b = bh >> 4;
    int qbase = qt * 128 + gw * 32;

    const unsigned short* Qh = Q  + (size_t)bh * SEQ * 64;
    const unsigned short* Kh = K  + (size_t)bh * SEQ * 64;
    const unsigned short* Vh = Vt + (size_t)bh * 64 * SEQ;
    // u32 mask words: 64 per q row; group g uses words g*32 .. g*32+31
    const unsigned* mrow32 = (const unsigned*)mbits +
        ((size_t)b * SEQ + qbase + l31) * 64 + g * 32;

    unsigned short* Kb0 = (unsigned short*)(smem + g * 16384);
    unsigned short* Kb1 = Kb0 + 2048;
    unsigned short* Vb0 = Kb0 + 4096;
    unsigned short* Vb1 = Kb0 + 6144;

    // staging geometry (per group: 256 threads cover K 4KB + V 4KB per tile)
    int krowS = (gw << 3) + (lane >> 3);        // 0..31
    int scK   = (lane & 7) ^ (krowS & 7);
    int vrowS = (gw << 4) + (lane >> 2);        // 0..63
    int scV   = (lane & 3) ^ (vrowS & 3);

    // Q B-frags: lane holds Q[qbase+l31][s*16 + hi*8 + j]
    bf16x8 qf[4];
    #pragma unroll
    for (int s = 0; s < 4; ++s)
        qf[s] = ld8(Qh + (size_t)(qbase + l31) * 64 + s * 16 + hi * 8);

    bf16x8 ones;
    #pragma unroll
    for (int i = 0; i < 8; ++i) ones[i] = (__bf16)1.0f;

    f32x16 o0 = {0.f,0.f,0.f,0.f,0.f,0.f,0.f,0.f,0.f,0.f,0.f,0.f,0.f,0.f,0.f,0.f};
    f32x16 o1 = o0;
    f32x16 ellD = o0;
    const float C = 0.125f * 1.44269504088896f;   // scale * log2(e)

    auto stage_tile = [&](unsigned short* Kd, unsigned short* Vd, int t) {
        int kk = kbase + t * 32;
        gload16(Kh + (size_t)(kk + krowS) * 64 + scK * 8, Kd + gw * 512);
        gload16(Vh + (size_t)vrowS * SEQ + kk + scV * 8, Vd + gw * 512);
    };

    auto compute_tile = [&](const unsigned short* Kc, const unsigned short* Vc, int t) {
        unsigned mword = mrow32[t];
        f32x16 z = {0.f,0.f,0.f,0.f,0.f,0.f,0.f,0.f,0.f,0.f,0.f,0.f,0.f,0.f,0.f,0.f};
        int krow = l31;
        #pragma unroll
        for (int s = 0; s < 4; ++s) {
            const unsigned short* kp =
                Kc + krow * 64 + ((((s << 1) + hi) ^ (krow & 7)) << 3);
            z = __builtin_amdgcn_mfma_f32_32x32x16_bf16(ld8(kp), qf[s], z, 0, 0, 0);
        }
        unsigned wsh = mword >> hi4;                 // lane's bits at 0..27
        unsigned wpk[8];
        #pragma unroll
        for (int rq = 0; rq < 4; ++rq) {
            #pragma unroll
            for (int rr = 0; rr < 2; ++rr) {
                float e[2];
                #pragma unroll
                for (int j = 0; j < 2; ++j) {
                    int pos = rq * 8 + 2 * rr + j;           // compile-time
                    int sx = (int)(wsh << (31 - pos)) >> 31; // v_bfe_i32
                    float bias = __builtin_bit_cast(float, (unsigned)sx & 0xFF800000u);
                    e[j] = fexp2(__builtin_fmaf(z[rq * 4 + 2 * rr + j], C, bias));
                }
                wpk[rq * 2 + rr] = (unsigned)f2bf(e[0]) | ((unsigned)f2bf(e[1]) << 16);
            }
        }
        __builtin_amdgcn_s_setprio(1);
        #pragma unroll
        for (int sl = 0; sl < 2; ++sl) {
            uint4v aw = {wpk[sl * 4 + 0], wpk[sl * 4 + 1],
                         wpk[sl * 4 + 2], wpk[sl * 4 + 3]};
            bf16x8 af = __builtin_bit_cast(bf16x8, aw);
            ellD = __builtin_amdgcn_mfma_f32_32x32x16_bf16(af, ones, ellD, 0, 0, 0);
            // V rows 32 cols wide (64B = 4 chunks), slot = chunk ^ (row & 3)
            int c0i = (((2 * sl)     ^ (l31 & 3)) << 3);
            int c1i = (((2 * sl + 1) ^ (l31 & 3)) << 3);
            {   // dtile 0: vrow = l31   ((32+l31)&3 == l31&3, so c?i shared)
                uint2v lo = *reinterpret_cast<const uint2v*>(Vc + l31 * 32 + c0i + hi4);
                uint2v hh = *reinterpret_cast<const uint2v*>(Vc + l31 * 32 + c1i + hi4);
                uint4v vw = {lo.x, lo.y, hh.x, hh.y};
                o0 = __builtin_amdgcn_mfma_f32_32x32x16_bf16(
                    af, __builtin_bit_cast(bf16x8, vw), o0, 0, 0, 0);
            }
            {   // dtile 1: vrow = 32 + l31
                uint2v lo = *reinterpret_cast<const uint2v*>(Vc + (32 + l31) * 32 + c0i + hi4);
                uint2v hh = *reinterpret_cast<const uint2v*>(Vc + (32 + l31) * 32 + c1i + hi4);
                uint4v vw = {lo.x, lo.y, hh.x, hh.y};
                o1 = __builtin_amdgcn_mfma_f32_32x32x16_bf16(
                    af, __builtin_bit_cast(bf16x8, vw), o1, 0, 0, 0);
            }
        }
        __builtin_amdgcn_s_setprio(0);
    };

    // prologue: stage tile 0 into buffer 0
    stage_tile(Kb0, Vb0, 0);
    __syncthreads();

    // 32 tiles per group, unrolled x2 (compile-time buffer roles)
    for (int t = 0; t < 32; t += 2) {
        stage_tile(Kb1, Vb1, t + 1);
        compute_tile(Kb0, Vb0, t);
        __syncthreads();
        if (t + 2 < 32) stage_tile(Kb0, Vb0, t + 2);
        compute_tile(Kb1, Vb1, t + 1);
        __syncthreads();
    }

    // ==== split-K combine ====
    // group A dumps partials lane-linear (conflict-free, no transpose)
    if (w < 4) {
        float* R = (float*)(smem + (size_t)w * 8448);
        #pragma unroll
        for (int reg = 0; reg < 16; ++reg) {
            R[reg * 64 + lane]        = o0[reg];
            R[(16 + reg) * 64 + lane] = o1[reg];
        }
        if (l31 == 0) {
            #pragma unroll
            for (int reg = 0; reg < 16; ++reg)
                R[2048 + (reg & 3) + 8 * (reg >> 2) + hi4] = ellD[reg];
        }
    }
    __syncthreads();
    if (w >= 4) {
        const float* R = (const float*)(smem + (size_t)(w - 4) * 8448);
        #pragma unroll
        for (int reg = 0; reg < 16; ++reg) {
            o0[reg]   += R[reg * 64 + lane];
            o1[reg]   += R[(16 + reg) * 64 + lane];
            ellD[reg] += R[2048 + (reg & 3) + 8 * (reg >> 2) + hi4];
        }
    }
    __syncthreads();   // fences partial reads before bf16 reuse of the region
    if (w >= 4) {
        // ==== fused epilogue: out = tanh(O @ Wfc + bfc) (R15-verified) ====
        unsigned short* Ot = (unsigned short*)(smem + (size_t)(w - 4) * 8448);
        #pragma unroll
        for (int reg = 0; reg < 16; ++reg) {
            float l = ellD[reg];
            float rcp = (l == 0.f) ? 0.f : __builtin_amdgcn_rcpf(l);
            int ql = (reg & 3) + 8 * (reg >> 2) + hi4;   // 0..31
            int ch0 = (l31 >> 3) ^ (ql & 7);
            int ch1 = ((l31 >> 3) + 4) ^ (ql & 7);
            Ot[ql * 64 + ch0 * 8 + (l31 & 7)] = f2bf(o0[reg] * rcp);
            Ot[ql * 64 + ch1 * 8 + (l31 & 7)] = f2bf(o1[reg] * rcp);
        }
        bf16x8 of[4];
        #pragma unroll
        for (int s = 0; s < 4; ++s) {
            int cs = (s * 2 + hi) ^ (l31 & 7);
            of[s] = ld8(Ot + l31 * 64 + cs * 8);
        }
        size_t orow = ((size_t)b * SEQ + qbase + l31) * NH + (bh & 15);
        #pragma unroll
        for (int ctile = 0; ctile < 2; ++ctile) {
            f32x16 acc = {0.f,0.f,0.f,0.f,0.f,0.f,0.f,0.f,0.f,0.f,0.f,0.f,0.f,0.f,0.f,0.f};
            #pragma unroll
            for (int s = 0; s < 4; ++s) {
                bf16x8 wf = ld8(WfcT + (ctile * 32 + l31) * 64 + s * 16 + hi * 8);
                acc = __builtin_amdgcn_mfma_f32_32x32x16_bf16(wf, of[s], acc, 0, 0, 0);
            }
            #pragma unroll
            for (int gq = 0; gq < 4; ++gq) {   // regs 4gq.. -> c = ctile*32+8gq+4hi+0..3
                int cbase = ctile * 32 + 8 * gq + hi4;
                f32x4 bv = *reinterpret_cast<const f32x4*>(bfc + cbase);
                f32x4 st;
                #pragma unroll
                for (int r = 0; r < 4; ++r) {
                    float x = acc[gq * 4 + r] + bv[r];
                    x = fminf(fmaxf(x, -9.f), 9.f);
                    float t = fexp2(x * 2.88539008177793f);     // 2*log2(e)
                    st[r] = (t - 1.f) * __builtin_amdgcn_rcpf(t + 1.f);
                }
                *reinterpret_cast<f32x4*>(out + orow * 64 + cbase) = st;
            }
        }
    }
}

extern "C" void kernel_launch(void* const* d_in, const int* in_sizes, int n_in,
                              void* d_out, int out_size, void* d_ws, size_t ws_size,
                              hipStream_t stream) {
    const float* q_origin = (const float*)d_in[0];
    const float* k_origin = (const float*)d_in[1];
    const int*   mask     = (const int*)d_in[2];
    const float* Wq       = (const float*)d_in[3];
    const float* Wk       = (const float*)d_in[4];
    const float* Wv       = (const float*)d_in[5];
    const float* Wfc      = (const float*)d_in[6];
    const float* bfc      = (const float*)d_in[7];
    float* out = (float*)d_out;

    unsigned short* ws = (unsigned short*)d_ws;
    unsigned short* qbf  = ws;                 // dead after proj
    unsigned short* kbf  = qbf  + TOK * DH;    // dead after proj
    unsigned short* WqT  = kbf  + TOK * DH;
    unsigned short* WkT  = WqT  + 64 * PROJC;
    unsigned short* WvT  = WkT  + 64 * PROJC;
    unsigned short* WfcT = WvT  + 64 * PROJC;
    unsigned short* Qb   = WfcT + 64 * 64;
    unsigned short* Kb   = Qb   + (size_t)BSZ * NH * SEQ * DH;
    unsigned short* Vtb  = Kb   + (size_t)BSZ * NH * SEQ * DH;
    unsigned long long* mbits = (unsigned long long*)d_ws;  // aliases qbf/kbf

    prep_kernel<<<4880, 256, 0, stream>>>(q_origin, k_origin, Wq, Wk, Wv, Wfc,
                                          qbf, kbf, WqT, WkT, WvT, WfcT);
    proj_kernel<<<dim3(TOK / 64, NH), 256, 0, stream>>>(
        qbf, kbf, WqT, WkT, WvT, Qb, Kb, Vtb);
    maskpack_kernel<<<(size_t)BSZ * SEQ * SEQ / 256, 256, 0, stream>>>(mask, mbits);
    attn_kernel<<<1024, 512, 0, stream>>>(Qb, Kb, Vtb, mbits, WfcT, bfc, out);
}

// Round 18
// 164.500 us; speedup vs baseline: 8.9534x; 1.1000x over previous
//
#include <hip/hip_runtime.h>
#include <hip/hip_bf16.h>

// Problem constants
#define BSZ 4
#define SEQ 2048
#define NH  16
#define DH  64
#define TOK (BSZ*SEQ)          // 8192 tokens
#define PROJC (NH*DH)          // 1024

typedef __bf16 bf16x8 __attribute__((ext_vector_type(8)));
typedef float  f32x4  __attribute__((ext_vector_type(4)));
typedef float  f32x16 __attribute__((ext_vector_type(16)));
typedef unsigned int uint4v __attribute__((ext_vector_type(4)));
typedef unsigned int uint2v __attribute__((ext_vector_type(2)));

__device__ inline unsigned short f2bf(float f) {
    __bf16 h = (__bf16)f;
    return __builtin_bit_cast(unsigned short, h);
}

__device__ inline bf16x8 ld8(const unsigned short* p) {
    return __builtin_bit_cast(bf16x8, *reinterpret_cast<const uint4v*>(p));
}

// raw v_exp_f32 (2^x): 1 instruction, no OCML range/denorm guards.
__device__ inline float fexp2(float x) {
    float r;
    asm("v_exp_f32 %0, %1" : "=v"(r) : "v"(x));
    return r;
}

// async global -> LDS, 16B per lane; LDS dest = wave-uniform base + lane*16
__device__ inline void gload16(const unsigned short* g, unsigned short* l) {
    __builtin_amdgcn_global_load_lds(
        (__attribute__((address_space(1))) void*)g,
        (__attribute__((address_space(3))) void*)l, 16, 0, 0);
}

// ---------------- fused prep: conv (f32->bf16) + 4x weight transpose -------
__global__ __launch_bounds__(256) void prep_kernel(const float* __restrict__ q,
                                                   const float* __restrict__ k,
                                                   const float* __restrict__ Wq,
                                                   const float* __restrict__ Wk,
                                                   const float* __restrict__ Wv,
                                                   const float* __restrict__ Wfc,
                                                   unsigned short* __restrict__ qbf,
                                                   unsigned short* __restrict__ kbf,
                                                   unsigned short* __restrict__ WqT,
                                                   unsigned short* __restrict__ WkT,
                                                   unsigned short* __restrict__ WvT,
                                                   unsigned short* __restrict__ WfcT) {
    int bx = blockIdx.x;
    if (bx < 4096) {
        int idx = (bx & 2047) * 256 + threadIdx.x;
        if (bx < 2048) qbf[idx] = f2bf(q[idx]);
        else           kbf[idx] = f2bf(k[idx]);
        return;
    }
    bx -= 4096;
    const float* W; unsigned short* WT; int cols; int base;
    if      (bx < 256) { W = Wq;  WT = WqT;  cols = PROJC; base = bx; }
    else if (bx < 512) { W = Wk;  WT = WkT;  cols = PROJC; base = bx - 256; }
    else if (bx < 768) { W = Wv;  WT = WvT;  cols = PROJC; base = bx - 512; }
    else               { W = Wfc; WT = WfcT; cols = 64;    base = bx - 768; }
    int idx = base * 256 + threadIdx.x;
    int c = idx % cols, kk = idx / cols;
    WT[c * 64 + kk] = f2bf(W[kk * cols + c]);
}

// ---------------- mask bit-pack: int32 [b][q][k] -> uint64 bitrows ---------
__global__ __launch_bounds__(256) void maskpack_kernel(const int* __restrict__ mask,
                                                       unsigned long long* __restrict__ mbits) {
    size_t gid = (size_t)blockIdx.x * 256 + threadIdx.x;
    int lane = threadIdx.x & 63;
    unsigned long long bal = __ballot(mask[gid] != 0);
    if (lane == 0) mbits[gid >> 6] = bal;
}

// ---------------- fused projections: Q, K, Vt; 4 heads per block -----------
// Grid (128 token-tiles, 4 head-groups), 256 threads. A-fragments (qbf, kbf)
// loaded ONCE and reused across 4 heads (cuts A re-read traffic 4x). Per
// head: 12 MFMA -> LDS tiles -> coalesced b128 write-out (R14-verified).
__global__ __launch_bounds__(256) void proj_kernel(const unsigned short* __restrict__ qbf,
                                                   const unsigned short* __restrict__ kbf,
                                                   const unsigned short* __restrict__ WqT,
                                                   const unsigned short* __restrict__ WkT,
                                                   const unsigned short* __restrict__ WvT,
                                                   unsigned short* __restrict__ Qo,
                                                   unsigned short* __restrict__ Ko,
                                                   unsigned short* __restrict__ Vto) {
    __shared__ __align__(16) unsigned short TQ[64][72];
    __shared__ __align__(16) unsigned short TK[64][72];
    __shared__ __align__(16) unsigned short TV[64][72];
    int tid = threadIdx.x, w = tid >> 6, lane = tid & 63;
    int l15 = lane & 15, l4 = lane >> 4;
    int r0 = blockIdx.x * 64 + w * 16;
    int b = blockIdx.x >> 5;
    int tq0 = (blockIdx.x & 31) * 64;       // token offset within batch
    int rl8 = tid >> 3, chunk = tid & 7;

    const unsigned short* aq = qbf + (r0 + l15) * 64 + l4 * 8;
    bf16x8 a0q = ld8(aq), a1q = ld8(aq + 32);
    const unsigned short* ak = kbf + (r0 + l15) * 64 + l4 * 8;
    bf16x8 a0k = ld8(ak), a1k = ld8(ak + 32);

    for (int hh = 0; hh < 4; ++hh) {
        int h = blockIdx.y * 4 + hh;
        int c0 = h * 64;
        size_t bh = (size_t)(b * NH + h);

        #pragma unroll
        for (int ct = 0; ct < 4; ++ct) {
            int wrow = (c0 + ct * 16 + l15) * 64 + l4 * 8;
            bf16x8 q0 = ld8(WqT + wrow), q1 = ld8(WqT + wrow + 32);
            bf16x8 k0 = ld8(WkT + wrow), k1 = ld8(WkT + wrow + 32);
            bf16x8 v0 = ld8(WvT + wrow), v1 = ld8(WvT + wrow + 32);
            f32x4 accq = {0.f,0.f,0.f,0.f}, acck = accq, accv = accq;
            accq = __builtin_amdgcn_mfma_f32_16x16x32_bf16(q0, a0q, accq, 0, 0, 0);
            accq = __builtin_amdgcn_mfma_f32_16x16x32_bf16(q1, a1q, accq, 0, 0, 0);
            acck = __builtin_amdgcn_mfma_f32_16x16x32_bf16(k0, a0k, acck, 0, 0, 0);
            acck = __builtin_amdgcn_mfma_f32_16x16x32_bf16(k1, a1k, acck, 0, 0, 0);
            accv = __builtin_amdgcn_mfma_f32_16x16x32_bf16(a0k, v0, accv, 0, 0, 0);
            accv = __builtin_amdgcn_mfma_f32_16x16x32_bf16(a1k, v1, accv, 0, 0, 0);
            uint2v pq, pk, pv;
            pq.x = (unsigned)f2bf(accq[0]) | ((unsigned)f2bf(accq[1]) << 16);
            pq.y = (unsigned)f2bf(accq[2]) | ((unsigned)f2bf(accq[3]) << 16);
            pk.x = (unsigned)f2bf(acck[0]) | ((unsigned)f2bf(acck[1]) << 16);
            pk.y = (unsigned)f2bf(acck[2]) | ((unsigned)f2bf(acck[3]) << 16);
            pv.x = (unsigned)f2bf(accv[0]) | ((unsigned)f2bf(accv[1]) << 16);
            pv.y = (unsigned)f2bf(accv[2]) | ((unsigned)f2bf(accv[3]) << 16);
            *reinterpret_cast<uint2v*>(&TQ[w * 16 + l15][ct * 16 + l4 * 4]) = pq;
            *reinterpret_cast<uint2v*>(&TK[w * 16 + l15][ct * 16 + l4 * 4]) = pk;
            *reinterpret_cast<uint2v*>(&TV[ct * 16 + l15][w * 16 + l4 * 4]) = pv;
        }
        __syncthreads();

        #pragma unroll
        for (int p = 0; p < 2; ++p) {
            int rl = p * 32 + rl8;
            uint4v vq = *reinterpret_cast<const uint4v*>(&TQ[rl][chunk * 8]);
            uint4v vk = *reinterpret_cast<const uint4v*>(&TK[rl][chunk * 8]);
            uint4v vv = *reinterpret_cast<const uint4v*>(&TV[rl][chunk * 8]);
            *reinterpret_cast<uint4v*>(Qo  + (bh * SEQ + tq0 + rl) * 64 + chunk * 8) = vq;
            *reinterpret_cast<uint4v*>(Ko  + (bh * SEQ + tq0 + rl) * 64 + chunk * 8) = vk;
            *reinterpret_cast<uint4v*>(Vto + (bh * 64 + rl) * SEQ + tq0 + chunk * 8) = vv;
        }
        if (hh < 3) __syncthreads();   // tiles reused next head
    }
}

// ---------------- flash attention + fused FC/tanh epilogue (R15) -----------
// Grid 512 (XCD-swizzled), 512 threads = 8 waves, 32 q rows per wave; 8
// waves share one K/V staging. K/V [64][64] double-buffered via
// global_load_lds; kb-loop unrolled x2. Swapped QK^T; PV A-frag = lane's own
// packed words; ell via ones-MFMA. Static max m=0; fully-masked -> ell==0.
// Epilogue: normalized bf16 O -> wave-private XOR-swizzled LDS tile ->
// B-frags -> out = tanh(O @ Wfc + bfc) via 8 mfma + packed dwordx4 stores.
__global__ __launch_bounds__(512, 4) void attn_kernel(const unsigned short* __restrict__ Q,
                                                      const unsigned short* __restrict__ K,
                                                      const unsigned short* __restrict__ Vt,
                                                      const unsigned long long* __restrict__ mbits,
                                                      const unsigned short* __restrict__ WfcT,
                                                      const float* __restrict__ bfc,
                                                      float* __restrict__ out) {
    __shared__ __align__(16) unsigned short Ks[2][64 * 64];   // 16 KB
    __shared__ __align__(16) unsigned short Vs[2][64 * 64];   // 16 KB
    int tid = threadIdx.x, w = tid >> 6, lane = tid & 63;
    int l31 = lane & 31, hi = lane >> 5;
    int hi4 = hi * 4;

    // XCD-aware swizzle: 512 % 8 == 0, bijective
    int bid = blockIdx.x;
    int swz = (bid & 7) * 64 + (bid >> 3);
    int bh = swz >> 3;              // 0..63
    int qt = swz & 7;               // 0..7
    int b = bh >> 4;
    int qbase = qt * 256 + w * 32;

    const unsigned short* Qh = Q  + (size_t)bh * SEQ * 64;
    const unsigned short* Kh = K  + (size_t)bh * SEQ * 64;
    const unsigned short* Vh = Vt + (size_t)bh * 64 * SEQ;
    const unsigned long long* mrow =
        mbits + ((size_t)b * SEQ + qbase + l31) * (SEQ / 64);

    // staging: 512 threads x 16B = full 8KB tile in one pass
    int row1 = (w << 3) + (lane >> 3);          // 0..63 across 8 waves
    int sc1 = (lane & 7) ^ (row1 & 7);          // source chunk (XOR involution)
    unsigned short* Kd0 = &Ks[0][0] + w * 512;
    unsigned short* Vd0 = &Vs[0][0] + w * 512;
    unsigned short* Kd1 = &Ks[1][0] + w * 512;
    unsigned short* Vd1 = &Vs[1][0] + w * 512;

    // Q B-frags: lane holds Q[qbase+l31][s*16 + hi*8 + j]
    bf16x8 qf[4];
    #pragma unroll
    for (int s = 0; s < 4; ++s)
        qf[s] = ld8(Qh + (size_t)(qbase + l31) * 64 + s * 16 + hi * 8);

    bf16x8 ones;
    #pragma unroll
    for (int i = 0; i < 8; ++i) ones[i] = (__bf16)1.0f;

    f32x16 o0 = {0.f,0.f,0.f,0.f,0.f,0.f,0.f,0.f,0.f,0.f,0.f,0.f,0.f,0.f,0.f,0.f};
    f32x16 o1 = o0;
    f32x16 ellD = o0;
    const float C = 0.125f * 1.44269504088896f;   // scale * log2(e)

    auto stage_tile = [&](unsigned short* Kd, unsigned short* Vd, int nkb) {
        gload16(Kh + (size_t)(nkb + row1) * 64 + sc1 * 8, Kd);
        gload16(Vh + (size_t)row1 * SEQ + nkb + sc1 * 8, Vd);
    };

    auto compute_tile = [&](const unsigned short* Kc, const unsigned short* Vc, int kb) {
        unsigned long long wb = mrow[kb >> 6];
        #pragma unroll
        for (int kt = 0; kt < 2; ++kt) {
            f32x16 z = {0.f,0.f,0.f,0.f,0.f,0.f,0.f,0.f,0.f,0.f,0.f,0.f,0.f,0.f,0.f,0.f};
            int krow = kt * 32 + l31;
            #pragma unroll
            for (int s = 0; s < 4; ++s) {
                const unsigned short* kp =
                    Kc + krow * 64 + ((((s << 1) + hi) ^ (krow & 7)) << 3);
                z = __builtin_amdgcn_mfma_f32_32x32x16_bf16(ld8(kp), qf[s], z, 0, 0, 0);
            }
            unsigned wsh = (unsigned)(wb >> (kt * 32)) >> hi4;  // lane's bits 0..27
            unsigned wpk[8];
            #pragma unroll
            for (int rq = 0; rq < 4; ++rq) {
                #pragma unroll
                for (int rr = 0; rr < 2; ++rr) {
                    float e[2];
                    #pragma unroll
                    for (int j = 0; j < 2; ++j) {
                        int pos = rq * 8 + 2 * rr + j;           // compile-time
                        int sx = (int)(wsh << (31 - pos)) >> 31; // v_bfe_i32
                        float bias = __builtin_bit_cast(float, (unsigned)sx & 0xFF800000u);
                        e[j] = fexp2(__builtin_fmaf(z[rq * 4 + 2 * rr + j], C, bias));
                    }
                    wpk[rq * 2 + rr] = (unsigned)f2bf(e[0]) | ((unsigned)f2bf(e[1]) << 16);
                }
            }
            __builtin_amdgcn_s_setprio(1);
            #pragma unroll
            for (int sl = 0; sl < 2; ++sl) {
                uint4v aw = {wpk[sl * 4 + 0], wpk[sl * 4 + 1],
                             wpk[sl * 4 + 2], wpk[sl * 4 + 3]};
                bf16x8 af = __builtin_bit_cast(bf16x8, aw);
                ellD = __builtin_amdgcn_mfma_f32_32x32x16_bf16(af, ones, ellD, 0, 0, 0);
                int n = kt * 2 + sl;            // k-subtile of 16 within kb
                {   // dtile 0
                    int vrow = l31;
                    int c0i = ((2 * n) ^ (vrow & 7)) << 3;
                    int c1i = ((2 * n + 1) ^ (vrow & 7)) << 3;
                    uint2v lo = *reinterpret_cast<const uint2v*>(Vc + vrow * 64 + c0i + hi4);
                    uint2v hh = *reinterpret_cast<const uint2v*>(Vc + vrow * 64 + c1i + hi4);
                    uint4v vw = {lo.x, lo.y, hh.x, hh.y};
                    o0 = __builtin_amdgcn_mfma_f32_32x32x16_bf16(
                        af, __builtin_bit_cast(bf16x8, vw), o0, 0, 0, 0);
                }
                {   // dtile 1
                    int vrow = 32 + l31;
                    int c0i = ((2 * n) ^ (vrow & 7)) << 3;
                    int c1i = ((2 * n + 1) ^ (vrow & 7)) << 3;
                    uint2v lo = *reinterpret_cast<const uint2v*>(Vc + vrow * 64 + c0i + hi4);
                    uint2v hh = *reinterpret_cast<const uint2v*>(Vc + vrow * 64 + c1i + hi4);
                    uint4v vw = {lo.x, lo.y, hh.x, hh.y};
                    o1 = __builtin_amdgcn_mfma_f32_32x32x16_bf16(
                        af, __builtin_bit_cast(bf16x8, vw), o1, 0, 0, 0);
                }
            }
            __builtin_amdgcn_s_setprio(0);
        }
    };

    // prologue: stage kb=0 into buffer 0
    stage_tile(Kd0, Vd0, 0);
    __syncthreads();

    for (int kb = 0; kb < SEQ; kb += 128) {
        stage_tile(Kd1, Vd1, kb + 64);
        compute_tile(&Ks[0][0], &Vs[0][0], kb);
        __syncthreads();
        if (kb + 128 < SEQ) stage_tile(Kd0, Vd0, kb + 128);
        compute_tile(&Ks[1][0], &Vs[1][0], kb + 64);
        __syncthreads();
    }

    // ==== fused epilogue: out = tanh(O @ Wfc + bfc) ====
    // wave-private 4KB LDS tile (reuse Ks/Vs; loop's final barrier passed)
    unsigned short* Ot = ((w < 4) ? &Ks[0][0] : &Vs[0][0]) + (w & 3) * 2048;

    // write normalized bf16 O, XOR-chunk swizzle: chunk ^= (q & 7)
    #pragma unroll
    for (int reg = 0; reg < 16; ++reg) {
        float l = ellD[reg];
        float rcp = (l == 0.f) ? 0.f : __builtin_amdgcn_rcpf(l);
        int ql = (reg & 3) + 8 * (reg >> 2) + hi4;   // 0..31
        int ch0 = (l31 >> 3) ^ (ql & 7);
        int ch1 = ((l31 >> 3) + 4) ^ (ql & 7);
        Ot[ql * 64 + ch0 * 8 + (l31 & 7)] = f2bf(o0[reg] * rcp);
        Ot[ql * 64 + ch1 * 8 + (l31 & 7)] = f2bf(o1[reg] * rcp);
    }
    // read B-frags: lane=q=l31 holds O[q][dd = s*16 + hi*8 + j]
    bf16x8 of[4];
    #pragma unroll
    for (int s = 0; s < 4; ++s) {
        int cs = (s * 2 + hi) ^ (l31 & 7);
        of[s] = ld8(Ot + l31 * 64 + cs * 8);
    }
    // FC: A = WfcT[c][dd] (same A-frag mapping as K in QK^T), B = O
    int qrow = qbase + l31;
    size_t orow = ((size_t)b * SEQ + qrow) * NH + (bh & 15);
    #pragma unroll
    for (int ctile = 0; ctile < 2; ++ctile) {
        f32x16 acc = {0.f,0.f,0.f,0.f,0.f,0.f,0.f,0.f,0.f,0.f,0.f,0.f,0.f,0.f,0.f,0.f};
        #pragma unroll
        for (int s = 0; s < 4; ++s) {
            bf16x8 wf = ld8(WfcT + (ctile * 32 + l31) * 64 + s * 16 + hi * 8);
            acc = __builtin_amdgcn_mfma_f32_32x32x16_bf16(wf, of[s], acc, 0, 0, 0);
        }
        #pragma unroll
        for (int g = 0; g < 4; ++g) {   // regs 4g..4g+3 -> c = ctile*32+8g+4hi+0..3
            int cbase = ctile * 32 + 8 * g + hi4;
            f32x4 bv = *reinterpret_cast<const f32x4*>(bfc + cbase);
            f32x4 st;
            #pragma unroll
            for (int r = 0; r < 4; ++r) {
                float x = acc[g * 4 + r] + bv[r];
                x = fminf(fmaxf(x, -9.f), 9.f);
                float t = fexp2(x * 2.88539008177793f);     // 2*log2(e)
                st[r] = (t - 1.f) * __builtin_amdgcn_rcpf(t + 1.f);
            }
            *reinterpret_cast<f32x4*>(out + orow * 64 + cbase) = st;
        }
    }
}

extern "C" void kernel_launch(void* const* d_in, const int* in_sizes, int n_in,
                              void* d_out, int out_size, void* d_ws, size_t ws_size,
                              hipStream_t stream) {
    const float* q_origin = (const float*)d_in[0];
    const float* k_origin = (const float*)d_in[1];
    const int*   mask     = (const int*)d_in[2];
    const float* Wq       = (const float*)d_in[3];
    const float* Wk       = (const float*)d_in[4];
    const float* Wv       = (const float*)d_in[5];
    const float* Wfc      = (const float*)d_in[6];
    const float* bfc      = (const float*)d_in[7];
    float* out = (float*)d_out;

    unsigned short* ws = (unsigned short*)d_ws;
    unsigned short* qbf  = ws;                 // dead after proj
    unsigned short* kbf  = qbf  + TOK * DH;    // dead after proj
    unsigned short* WqT  = kbf  + TOK * DH;
    unsigned short* WkT  = WqT  + 64 * PROJC;
    unsigned short* WvT  = WkT  + 64 * PROJC;
    unsigned short* WfcT = WvT  + 64 * PROJC;
    unsigned short* Qb   = WfcT + 64 * 64;
    unsigned short* Kb   = Qb   + (size_t)BSZ * NH * SEQ * DH;
    unsigned short* Vtb  = Kb   + (size_t)BSZ * NH * SEQ * DH;
    unsigned long long* mbits = (unsigned long long*)d_ws;  // aliases qbf/kbf

    prep_kernel<<<4880, 256, 0, stream>>>(q_origin, k_origin, Wq, Wk, Wv, Wfc,
                                          qbf, kbf, WqT, WkT, WvT, WfcT);
    proj_kernel<<<dim3(TOK / 64, NH / 4), 256, 0, stream>>>(
        qbf, kbf, WqT, WkT, WvT, Qb, Kb, Vtb);
    maskpack_kernel<<<(size_t)BSZ * SEQ * SEQ / 256, 256, 0, stream>>>(mask, mbits);
    attn_kernel<<<512, 512, 0, stream>>>(Qb, Kb, Vtb, mbits, WfcT, bfc, out);
}

// Round 19
// 161.458 us; speedup vs baseline: 9.1221x; 1.0188x over previous
//
#include <hip/hip_runtime.h>
#include <hip/hip_bf16.h>

// Problem constants
#define BSZ 4
#define SEQ 2048
#define NH  16
#define DH  64
#define TOK (BSZ*SEQ)          // 8192 tokens
#define PROJC (NH*DH)          // 1024

typedef __bf16 bf16x8 __attribute__((ext_vector_type(8)));
typedef float  f32x4  __attribute__((ext_vector_type(4)));
typedef float  f32x16 __attribute__((ext_vector_type(16)));
typedef unsigned int uint4v __attribute__((ext_vector_type(4)));
typedef unsigned int uint2v __attribute__((ext_vector_type(2)));

__device__ inline unsigned short f2bf(float f) {
    __bf16 h = (__bf16)f;
    return __builtin_bit_cast(unsigned short, h);
}

__device__ inline bf16x8 ld8(const unsigned short* p) {
    return __builtin_bit_cast(bf16x8, *reinterpret_cast<const uint4v*>(p));
}

// load 8 consecutive f32 and convert to a bf16x8 fragment (same rounding as
// the old conv+ld8 path: one f2bf per element)
__device__ inline bf16x8 ld8f(const float* p) {
    f32x4 a = *reinterpret_cast<const f32x4*>(p);
    f32x4 b = *reinterpret_cast<const f32x4*>(p + 4);
    uint4v r;
    r.x = (unsigned)f2bf(a[0]) | ((unsigned)f2bf(a[1]) << 16);
    r.y = (unsigned)f2bf(a[2]) | ((unsigned)f2bf(a[3]) << 16);
    r.z = (unsigned)f2bf(b[0]) | ((unsigned)f2bf(b[1]) << 16);
    r.w = (unsigned)f2bf(b[2]) | ((unsigned)f2bf(b[3]) << 16);
    return __builtin_bit_cast(bf16x8, r);
}

// raw v_exp_f32 (2^x): 1 instruction, no OCML range/denorm guards.
__device__ inline float fexp2(float x) {
    float r;
    asm("v_exp_f32 %0, %1" : "=v"(r) : "v"(x));
    return r;
}

// async global -> LDS, 16B per lane; LDS dest = wave-uniform base + lane*16
__device__ inline void gload16(const unsigned short* g, unsigned short* l) {
    __builtin_amdgcn_global_load_lds(
        (__attribute__((address_space(1))) void*)g,
        (__attribute__((address_space(3))) void*)l, 16, 0, 0);
}

// ---------------- fused prep: weight transposes + mask bit-pack ------------
// blocks 0..255: WqT ; 256..511: WkT ; 512..767: WvT ; 768..783: WfcT ;
// 784..66319: maskpack (16M int32 -> 2MB bitmask, non-aliasing region).
__global__ __launch_bounds__(256) void prep_kernel(const float* __restrict__ Wq,
                                                   const float* __restrict__ Wk,
                                                   const float* __restrict__ Wv,
                                                   const float* __restrict__ Wfc,
                                                   const int* __restrict__ mask,
                                                   unsigned short* __restrict__ WqT,
                                                   unsigned short* __restrict__ WkT,
                                                   unsigned short* __restrict__ WvT,
                                                   unsigned short* __restrict__ WfcT,
                                                   unsigned long long* __restrict__ mbits) {
    int bx = blockIdx.x;
    if (bx >= 784) {
        size_t gid = (size_t)(bx - 784) * 256 + threadIdx.x;
        int lane = threadIdx.x & 63;
        unsigned long long bal = __ballot(mask[gid] != 0);
        if (lane == 0) mbits[gid >> 6] = bal;
        return;
    }
    const float* W; unsigned short* WT; int cols; int base;
    if      (bx < 256) { W = Wq;  WT = WqT;  cols = PROJC; base = bx; }
    else if (bx < 512) { W = Wk;  WT = WkT;  cols = PROJC; base = bx - 256; }
    else if (bx < 768) { W = Wv;  WT = WvT;  cols = PROJC; base = bx - 512; }
    else               { W = Wfc; WT = WfcT; cols = 64;    base = bx - 768; }
    int idx = base * 256 + threadIdx.x;
    int c = idx % cols, kk = idx / cols;
    WT[c * 64 + kk] = f2bf(W[kk * cols + c]);
}

// ---------------- fused projections: Q, K, Vt; 4 heads per block -----------
// Grid (128 token-tiles, 4 head-groups), 256 threads. A-fragments read
// DIRECTLY from f32 q_origin/k_origin (in-register convert — conv kernel
// deleted), loaded once and reused across 4 heads. Per head: 12 MFMA ->
// LDS tiles -> coalesced b128 write-out (R14-verified).
__global__ __launch_bounds__(256) void proj_kernel(const float* __restrict__ qorg,
                                                   const float* __restrict__ korg,
                                                   const unsigned short* __restrict__ WqT,
                                                   const unsigned short* __restrict__ WkT,
                                                   const unsigned short* __restrict__ WvT,
                                                   unsigned short* __restrict__ Qo,
                                                   unsigned short* __restrict__ Ko,
                                                   unsigned short* __restrict__ Vto) {
    __shared__ __align__(16) unsigned short TQ[64][72];
    __shared__ __align__(16) unsigned short TK[64][72];
    __shared__ __align__(16) unsigned short TV[64][72];
    int tid = threadIdx.x, w = tid >> 6, lane = tid & 63;
    int l15 = lane & 15, l4 = lane >> 4;
    int r0 = blockIdx.x * 64 + w * 16;
    int b = blockIdx.x >> 5;
    int tq0 = (blockIdx.x & 31) * 64;       // token offset within batch
    int rl8 = tid >> 3, chunk = tid & 7;

    const float* aqp = qorg + (size_t)(r0 + l15) * 64 + l4 * 8;
    bf16x8 a0q = ld8f(aqp), a1q = ld8f(aqp + 32);
    const float* akp = korg + (size_t)(r0 + l15) * 64 + l4 * 8;
    bf16x8 a0k = ld8f(akp), a1k = ld8f(akp + 32);

    for (int hh = 0; hh < 4; ++hh) {
        int h = blockIdx.y * 4 + hh;
        int c0 = h * 64;
        size_t bh = (size_t)(b * NH + h);

        #pragma unroll
        for (int ct = 0; ct < 4; ++ct) {
            int wrow = (c0 + ct * 16 + l15) * 64 + l4 * 8;
            bf16x8 q0 = ld8(WqT + wrow), q1 = ld8(WqT + wrow + 32);
            bf16x8 k0 = ld8(WkT + wrow), k1 = ld8(WkT + wrow + 32);
            bf16x8 v0 = ld8(WvT + wrow), v1 = ld8(WvT + wrow + 32);
            f32x4 accq = {0.f,0.f,0.f,0.f}, acck = accq, accv = accq;
            accq = __builtin_amdgcn_mfma_f32_16x16x32_bf16(q0, a0q, accq, 0, 0, 0);
            accq = __builtin_amdgcn_mfma_f32_16x16x32_bf16(q1, a1q, accq, 0, 0, 0);
            acck = __builtin_amdgcn_mfma_f32_16x16x32_bf16(k0, a0k, acck, 0, 0, 0);
            acck = __builtin_amdgcn_mfma_f32_16x16x32_bf16(k1, a1k, acck, 0, 0, 0);
            accv = __builtin_amdgcn_mfma_f32_16x16x32_bf16(a0k, v0, accv, 0, 0, 0);
            accv = __builtin_amdgcn_mfma_f32_16x16x32_bf16(a1k, v1, accv, 0, 0, 0);
            uint2v pq, pk, pv;
            pq.x = (unsigned)f2bf(accq[0]) | ((unsigned)f2bf(accq[1]) << 16);
            pq.y = (unsigned)f2bf(accq[2]) | ((unsigned)f2bf(accq[3]) << 16);
            pk.x = (unsigned)f2bf(acck[0]) | ((unsigned)f2bf(acck[1]) << 16);
            pk.y = (unsigned)f2bf(acck[2]) | ((unsigned)f2bf(acck[3]) << 16);
            pv.x = (unsigned)f2bf(accv[0]) | ((unsigned)f2bf(accv[1]) << 16);
            pv.y = (unsigned)f2bf(accv[2]) | ((unsigned)f2bf(accv[3]) << 16);
            *reinterpret_cast<uint2v*>(&TQ[w * 16 + l15][ct * 16 + l4 * 4]) = pq;
            *reinterpret_cast<uint2v*>(&TK[w * 16 + l15][ct * 16 + l4 * 4]) = pk;
            *reinterpret_cast<uint2v*>(&TV[ct * 16 + l15][w * 16 + l4 * 4]) = pv;
        }
        __syncthreads();

        #pragma unroll
        for (int p = 0; p < 2; ++p) {
            int rl = p * 32 + rl8;
            uint4v vq = *reinterpret_cast<const uint4v*>(&TQ[rl][chunk * 8]);
            uint4v vk = *reinterpret_cast<const uint4v*>(&TK[rl][chunk * 8]);
            uint4v vv = *reinterpret_cast<const uint4v*>(&TV[rl][chunk * 8]);
            *reinterpret_cast<uint4v*>(Qo  + (bh * SEQ + tq0 + rl) * 64 + chunk * 8) = vq;
            *reinterpret_cast<uint4v*>(Ko  + (bh * SEQ + tq0 + rl) * 64 + chunk * 8) = vk;
            *reinterpret_cast<uint4v*>(Vto + (bh * 64 + rl) * SEQ + tq0 + chunk * 8) = vv;
        }
        if (hh < 3) __syncthreads();   // tiles reused next head
    }
}

// ---------------- flash attention + fused FC/tanh epilogue (R15/R18) -------
// Grid 512 (XCD-swizzled), 512 threads = 8 waves, 32 q rows per wave; 8
// waves share one K/V staging. K/V [64][64] double-buffered via
// global_load_lds; kb-loop unrolled x2. Swapped QK^T; PV A-frag = lane's own
// packed words; ell via ones-MFMA. Static max m=0; fully-masked -> ell==0.
// Epilogue: normalized bf16 O -> wave-private XOR-swizzled LDS tile ->
// B-frags -> out = tanh(O @ Wfc + bfc) via 8 mfma + packed dwordx4 stores.
__global__ __launch_bounds__(512, 4) void attn_kernel(const unsigned short* __restrict__ Q,
                                                      const unsigned short* __restrict__ K,
                                                      const unsigned short* __restrict__ Vt,
                                                      const unsigned long long* __restrict__ mbits,
                                                      const unsigned short* __restrict__ WfcT,
                                                      const float* __restrict__ bfc,
                                                      float* __restrict__ out) {
    __shared__ __align__(16) unsigned short Ks[2][64 * 64];   // 16 KB
    __shared__ __align__(16) unsigned short Vs[2][64 * 64];   // 16 KB
    int tid = threadIdx.x, w = tid >> 6, lane = tid & 63;
    int l31 = lane & 31, hi = lane >> 5;
    int hi4 = hi * 4;

    // XCD-aware swizzle: 512 % 8 == 0, bijective
    int bid = blockIdx.x;
    int swz = (bid & 7) * 64 + (bid >> 3);
    int bh = swz >> 3;              // 0..63
    int qt = swz & 7;               // 0..7
    int b = bh >> 4;
    int qbase = qt * 256 + w * 32;

    const unsigned short* Qh = Q  + (size_t)bh * SEQ * 64;
    const unsigned short* Kh = K  + (size_t)bh * SEQ * 64;
    const unsigned short* Vh = Vt + (size_t)bh * 64 * SEQ;
    const unsigned long long* mrow =
        mbits + ((size_t)b * SEQ + qbase + l31) * (SEQ / 64);

    // staging: 512 threads x 16B = full 8KB tile in one pass
    int row1 = (w << 3) + (lane >> 3);          // 0..63 across 8 waves
    int sc1 = (lane & 7) ^ (row1 & 7);          // source chunk (XOR involution)
    unsigned short* Kd0 = &Ks[0][0] + w * 512;
    unsigned short* Vd0 = &Vs[0][0] + w * 512;
    unsigned short* Kd1 = &Ks[1][0] + w * 512;
    unsigned short* Vd1 = &Vs[1][0] + w * 512;

    // Q B-frags: lane holds Q[qbase+l31][s*16 + hi*8 + j]
    bf16x8 qf[4];
    #pragma unroll
    for (int s = 0; s < 4; ++s)
        qf[s] = ld8(Qh + (size_t)(qbase + l31) * 64 + s * 16 + hi * 8);

    bf16x8 ones;
    #pragma unroll
    for (int i = 0; i < 8; ++i) ones[i] = (__bf16)1.0f;

    f32x16 o0 = {0.f,0.f,0.f,0.f,0.f,0.f,0.f,0.f,0.f,0.f,0.f,0.f,0.f,0.f,0.f,0.f};
    f32x16 o1 = o0;
    f32x16 ellD = o0;
    const float C = 0.125f * 1.44269504088896f;   // scale * log2(e)

    auto stage_tile = [&](unsigned short* Kd, unsigned short* Vd, int nkb) {
        gload16(Kh + (size_t)(nkb + row1) * 64 + sc1 * 8, Kd);
        gload16(Vh + (size_t)row1 * SEQ + nkb + sc1 * 8, Vd);
    };

    auto compute_tile = [&](const unsigned short* Kc, const unsigned short* Vc, int kb) {
        unsigned long long wb = mrow[kb >> 6];
        #pragma unroll
        for (int kt = 0; kt < 2; ++kt) {
            f32x16 z = {0.f,0.f,0.f,0.f,0.f,0.f,0.f,0.f,0.f,0.f,0.f,0.f,0.f,0.f,0.f,0.f};
            int krow = kt * 32 + l31;
            #pragma unroll
            for (int s = 0; s < 4; ++s) {
                const unsigned short* kp =
                    Kc + krow * 64 + ((((s << 1) + hi) ^ (krow & 7)) << 3);
                z = __builtin_amdgcn_mfma_f32_32x32x16_bf16(ld8(kp), qf[s], z, 0, 0, 0);
            }
            unsigned wsh = (unsigned)(wb >> (kt * 32)) >> hi4;  // lane's bits 0..27
            unsigned wpk[8];
            #pragma unroll
            for (int rq = 0; rq < 4; ++rq) {
                #pragma unroll
                for (int rr = 0; rr < 2; ++rr) {
                    float e[2];
                    #pragma unroll
                    for (int j = 0; j < 2; ++j) {
                        int pos = rq * 8 + 2 * rr + j;           // compile-time
                        int sx = (int)(wsh << (31 - pos)) >> 31; // v_bfe_i32
                        float bias = __builtin_bit_cast(float, (unsigned)sx & 0xFF800000u);
                        e[j] = fexp2(__builtin_fmaf(z[rq * 4 + 2 * rr + j], C, bias));
                    }
                    wpk[rq * 2 + rr] = (unsigned)f2bf(e[0]) | ((unsigned)f2bf(e[1]) << 16);
                }
            }
            __builtin_amdgcn_s_setprio(1);
            #pragma unroll
            for (int sl = 0; sl < 2; ++sl) {
                uint4v aw = {wpk[sl * 4 + 0], wpk[sl * 4 + 1],
                             wpk[sl * 4 + 2], wpk[sl * 4 + 3]};
                bf16x8 af = __builtin_bit_cast(bf16x8, aw);
                ellD = __builtin_amdgcn_mfma_f32_32x32x16_bf16(af, ones, ellD, 0, 0, 0);
                int n = kt * 2 + sl;            // k-subtile of 16 within kb
                {   // dtile 0
                    int vrow = l31;
                    int c0i = ((2 * n) ^ (vrow & 7)) << 3;
                    int c1i = ((2 * n + 1) ^ (vrow & 7)) << 3;
                    uint2v lo = *reinterpret_cast<const uint2v*>(Vc + vrow * 64 + c0i + hi4);
                    uint2v hh = *reinterpret_cast<const uint2v*>(Vc + vrow * 64 + c1i + hi4);
                    uint4v vw = {lo.x, lo.y, hh.x, hh.y};
                    o0 = __builtin_amdgcn_mfma_f32_32x32x16_bf16(
                        af, __builtin_bit_cast(bf16x8, vw), o0, 0, 0, 0);
                }
                {   // dtile 1
                    int vrow = 32 + l31;
                    int c0i = ((2 * n) ^ (vrow & 7)) << 3;
                    int c1i = ((2 * n + 1) ^ (vrow & 7)) << 3;
                    uint2v lo = *reinterpret_cast<const uint2v*>(Vc + vrow * 64 + c0i + hi4);
                    uint2v hh = *reinterpret_cast<const uint2v*>(Vc + vrow * 64 + c1i + hi4);
                    uint4v vw = {lo.x, lo.y, hh.x, hh.y};
                    o1 = __builtin_amdgcn_mfma_f32_32x32x16_bf16(
                        af, __builtin_bit_cast(bf16x8, vw), o1, 0, 0, 0);
                }
            }
            __builtin_amdgcn_s_setprio(0);
        }
    };

    // prologue: stage kb=0 into buffer 0
    stage_tile(Kd0, Vd0, 0);
    __syncthreads();

    for (int kb = 0; kb < SEQ; kb += 128) {
        stage_tile(Kd1, Vd1, kb + 64);
        compute_tile(&Ks[0][0], &Vs[0][0], kb);
        __syncthreads();
        if (kb + 128 < SEQ) stage_tile(Kd0, Vd0, kb + 128);
        compute_tile(&Ks[1][0], &Vs[1][0], kb + 64);
        __syncthreads();
    }

    // ==== fused epilogue: out = tanh(O @ Wfc + bfc) ====
    // wave-private 4KB LDS tile (reuse Ks/Vs; loop's final barrier passed)
    unsigned short* Ot = ((w < 4) ? &Ks[0][0] : &Vs[0][0]) + (w & 3) * 2048;

    // write normalized bf16 O, XOR-chunk swizzle: chunk ^= (q & 7)
    #pragma unroll
    for (int reg = 0; reg < 16; ++reg) {
        float l = ellD[reg];
        float rcp = (l == 0.f) ? 0.f : __builtin_amdgcn_rcpf(l);
        int ql = (reg & 3) + 8 * (reg >> 2) + hi4;   // 0..31
        int ch0 = (l31 >> 3) ^ (ql & 7);
        int ch1 = ((l31 >> 3) + 4) ^ (ql & 7);
        Ot[ql * 64 + ch0 * 8 + (l31 & 7)] = f2bf(o0[reg] * rcp);
        Ot[ql * 64 + ch1 * 8 + (l31 & 7)] = f2bf(o1[reg] * rcp);
    }
    // read B-frags: lane=q=l31 holds O[q][dd = s*16 + hi*8 + j]
    bf16x8 of[4];
    #pragma unroll
    for (int s = 0; s < 4; ++s) {
        int cs = (s * 2 + hi) ^ (l31 & 7);
        of[s] = ld8(Ot + l31 * 64 + cs * 8);
    }
    // FC: A = WfcT[c][dd] (same A-frag mapping as K in QK^T), B = O
    int qrow = qbase + l31;
    size_t orow = ((size_t)b * SEQ + qrow) * NH + (bh & 15);
    #pragma unroll
    for (int ctile = 0; ctile < 2; ++ctile) {
        f32x16 acc = {0.f,0.f,0.f,0.f,0.f,0.f,0.f,0.f,0.f,0.f,0.f,0.f,0.f,0.f,0.f,0.f};
        #pragma unroll
        for (int s = 0; s < 4; ++s) {
            bf16x8 wf = ld8(WfcT + (ctile * 32 + l31) * 64 + s * 16 + hi * 8);
            acc = __builtin_amdgcn_mfma_f32_32x32x16_bf16(wf, of[s], acc, 0, 0, 0);
        }
        #pragma unroll
        for (int g = 0; g < 4; ++g) {   // regs 4g..4g+3 -> c = ctile*32+8g+4hi+0..3
            int cbase = ctile * 32 + 8 * g + hi4;
            f32x4 bv = *reinterpret_cast<const f32x4*>(bfc + cbase);
            f32x4 st;
            #pragma unroll
            for (int r = 0; r < 4; ++r) {
                float x = acc[g * 4 + r] + bv[r];
                x = fminf(fmaxf(x, -9.f), 9.f);
                float t = fexp2(x * 2.88539008177793f);     // 2*log2(e)
                st[r] = (t - 1.f) * __builtin_amdgcn_rcpf(t + 1.f);
            }
            *reinterpret_cast<f32x4*>(out + orow * 64 + cbase) = st;
        }
    }
}

extern "C" void kernel_launch(void* const* d_in, const int* in_sizes, int n_in,
                              void* d_out, int out_size, void* d_ws, size_t ws_size,
                              hipStream_t stream) {
    const float* q_origin = (const float*)d_in[0];
    const float* k_origin = (const float*)d_in[1];
    const int*   mask     = (const int*)d_in[2];
    const float* Wq       = (const float*)d_in[3];
    const float* Wk       = (const float*)d_in[4];
    const float* Wv       = (const float*)d_in[5];
    const float* Wfc      = (const float*)d_in[6];
    const float* bfc      = (const float*)d_in[7];
    float* out = (float*)d_out;

    unsigned short* ws = (unsigned short*)d_ws;
    // keep legacy offsets (qbf/kbf slots now unused but cheap)
    unsigned short* WqT  = ws + 2 * TOK * DH;
    unsigned short* WkT  = WqT  + 64 * PROJC;
    unsigned short* WvT  = WkT  + 64 * PROJC;
    unsigned short* WfcT = WvT  + 64 * PROJC;
    unsigned short* Qb   = WfcT + 64 * 64;
    unsigned short* Kb   = Qb   + (size_t)BSZ * NH * SEQ * DH;
    unsigned short* Vtb  = Kb   + (size_t)BSZ * NH * SEQ * DH;
    // mbits in its own region AFTER Vtb (old Ob slot, within ws_size) — no
    // aliasing, so maskpack can run fused with prep before proj.
    unsigned long long* mbits =
        (unsigned long long*)(Vtb + (size_t)BSZ * NH * SEQ * DH);

    prep_kernel<<<784 + (size_t)BSZ * SEQ * SEQ / 256, 256, 0, stream>>>(
        Wq, Wk, Wv, Wfc, mask, WqT, WkT, WvT, WfcT, mbits);
    proj_kernel<<<dim3(TOK / 64, NH / 4), 256, 0, stream>>>(
        q_origin, k_origin, WqT, WkT, WvT, Qb, Kb, Vtb);
    attn_kernel<<<512, 512, 0, stream>>>(Qb, Kb, Vtb, mbits, WfcT, bfc, out);
}